// Round 10
// baseline (428.863 us; speedup 1.0000x reference)
//
#include <hip/hip_runtime.h>
#include <cstdint>
#include <cstddef>

typedef __attribute__((ext_vector_type(4))) float f32x4;
typedef _Float16 h16x8 __attribute__((ext_vector_type(8)));

#define BLOCK 256
#define GRID  2048
#define NB    4

__device__ __forceinline__ uint32_t pk16(float a, float b) {
    // lo half = cvt(a), hi half = cvt(b), round-toward-zero
    return __builtin_bit_cast(uint32_t, __builtin_amdgcn_cvt_pkrtz(a, b));
}

// Lane l: p16 = l&15, g = l>>4. Element->feature convention for every MFMA
// operand: element j of chunk s <-> k = 32s + 8g + j (round-3/5/9-verified mirror).
__global__ __launch_bounds__(BLOCK, 8) void postpro_kernel(
    const float* __restrict__ prob,
    const float* __restrict__ W1,
    const float* __restrict__ b1,
    const float* __restrict__ W2,
    const float* __restrict__ b2,
    float* __restrict__ out,
    int nBatch, int bpw)
{
    __shared__ float sw[640];    // [0:512) W1 rows 0..3, [512:640) b1
    __shared__ float sW2[384];   // W2 [128][3] row-major, staged for fragment build
    const int tid = threadIdx.x;
    for (int i = tid; i < 512; i += BLOCK) sw[i] = W1[i];
    for (int i = tid; i < 128; i += BLOCK) sw[512 + i] = b1[i];
    for (int i = tid; i < 384; i += BLOCK) sW2[i] = W2[i];

    const int lane = tid & 63;
    const int p16  = lane & 15;
    const int g    = lane >> 4;
    const float fn = (float)p16;

    const int wave = blockIdx.x * (BLOCK / 64) + (tid >> 6);
    const int b0   = wave * bpw;

    // group-0 prob loads issued before the barrier (global, no LDS dependency)
    float p0[NB], p1[NB], p2[NB];
    #pragma unroll
    for (int u = 0; u < NB; ++u) {
        int b = b0 + u; if (b > nBatch - 1) b = nBatch - 1;
        const float* pp = prob + (size_t)b * 48 + p16 * 3;
        p0[u] = pp[0]; p1[u] = pp[1]; p2[u] = pp[2];
    }

    __syncthreads();   // LDS ready

    // W2 B-frags (fp16) from LDS: element j of chunk s = W2[32s+8g+j][c=p16], 0 for c>=3.
    // Gather addrs (3k+c) mod 32 are all distinct across the 12 active lanes: conflict-free.
    h16x8 w2f[4];
    #pragma unroll
    for (int s = 0; s < 4; ++s) {
        union { h16x8 v; _Float16 h[8]; } pk;
        #pragma unroll
        for (int j = 0; j < 8; ++j) {
            const int k = 32 * s + 8 * g + j;
            pk.h[j] = (p16 < 3) ? (_Float16)sW2[k * 3 + p16] : (_Float16)0.0f;
        }
        w2f[s] = pk.v;
    }
    const float binit = (p16 < 3) ? b2[p16] : 0.0f;   // b2 fold: sum(attn)=1
    const f32x4 yinit = {binit, binit, binit, binit};
    const f32x4 zero4 = {0.f, 0.f, 0.f, 0.f};

    #pragma unroll 1
    for (int bi = 0; bi < bpw; bi += NB) {
        const int bb = b0 + bi;

        if (bi != 0) {   // later groups load their probs here
            #pragma unroll
            for (int u = 0; u < NB; ++u) {
                int b = bb + u; if (b > nBatch - 1) b = nBatch - 1;
                const float* pp = prob + (size_t)b * 48 + p16 * 3;
                p0[u] = pp[0]; p1[u] = pp[1]; p2[u] = pp[2];
            }
        }

        f32x4 accS[NB], accY[NB];
        #pragma unroll
        for (int u = 0; u < NB; ++u) { accS[u] = zero4; accY[u] = yinit; }

        #pragma unroll
        for (int s = 0; s < 4; ++s) {
            const int h0 = 32 * s + 8 * g;
            const f32x4 r0a = *(const f32x4*)(sw + h0);
            const f32x4 r0b = *(const f32x4*)(sw + h0 + 4);
            const f32x4 r1a = *(const f32x4*)(sw + 128 + h0);
            const f32x4 r1b = *(const f32x4*)(sw + 128 + h0 + 4);
            const f32x4 r2a = *(const f32x4*)(sw + 256 + h0);
            const f32x4 r2b = *(const f32x4*)(sw + 256 + h0 + 4);
            const f32x4 w3a = *(const f32x4*)(sw + 384 + h0);
            const f32x4 w3b = *(const f32x4*)(sw + 384 + h0 + 4);
            const f32x4 b1a = *(const f32x4*)(sw + 512 + h0);
            const f32x4 b1b = *(const f32x4*)(sw + 512 + h0 + 4);

            float r0_[8], r1_[8], r2_[8], base_[8];
            #pragma unroll
            for (int j = 0; j < 4; ++j) {
                r0_[j] = r0a[j]; r0_[4 + j] = r0b[j];
                r1_[j] = r1a[j]; r1_[4 + j] = r1b[j];
                r2_[j] = r2a[j]; r2_[4 + j] = r2b[j];
                base_[j]     = fmaf(fn, w3a[j], b1a[j]);   // batch-invariant
                base_[4 + j] = fmaf(fn, w3b[j], b1b[j]);
            }

            #pragma unroll
            for (int u = 0; u < NB; ++u) {
                float H[8];
                #pragma unroll
                for (int j = 0; j < 8; ++j) {
                    float h = fmaf(p0[u], r0_[j], base_[j]);
                    h = fmaf(p1[u], r1_[j], h);
                    h = fmaf(p2[u], r2_[j], h);
                    H[j] = fmaxf(h, 0.0f);
                }
                union { h16x8 v; uint32_t q[4]; } Hf;
                #pragma unroll
                for (int t = 0; t < 4; ++t) Hf.q[t] = pk16(H[2 * t], H[2 * t + 1]);

                accS[u] = __builtin_amdgcn_mfma_f32_16x16x32_f16(Hf.v, Hf.v,   accS[u], 0, 0, 0);
                accY[u] = __builtin_amdgcn_mfma_f32_16x16x32_f16(Hf.v, w2f[s], accY[u], 0, 0, 0);
            }
        }

        #pragma unroll
        for (int u = 0; u < NB; ++u) {
            const int b = bb + u;
            // transposed softmax: accS[u][r] = S[4g+r][p16] = S[p16][4g+r] (symmetric)
            float m0 = fmaxf(fmaxf(accS[u][0], accS[u][1]), fmaxf(accS[u][2], accS[u][3]));
            m0 = fmaxf(m0, __shfl_xor(m0, 16));
            m0 = fmaxf(m0, __shfl_xor(m0, 32));
            const float e0 = __expf(accS[u][0] - m0);
            const float e1 = __expf(accS[u][1] - m0);
            const float e2 = __expf(accS[u][2] - m0);
            const float e3 = __expf(accS[u][3] - m0);
            float sm = (e0 + e1) + (e2 + e3);
            sm += __shfl_xor(sm, 16);
            sm += __shfl_xor(sm, 32);
            const float inv = __builtin_amdgcn_rcpf(sm);

            // epilogue: D[c][m] = sum_k Y'^T[c][k] attn^T[k][m], K=16 logical.
            union { h16x8 v; uint32_t q[4]; } Afr, Bfr;
            Afr.q[0] = pk16(accY[u][0], accY[u][1]);
            Afr.q[1] = pk16(accY[u][2], accY[u][3]);
            Afr.q[2] = 0u; Afr.q[3] = 0u;
            Bfr.q[0] = pk16(e0 * inv, e1 * inv);
            Bfr.q[1] = pk16(e2 * inv, e3 * inv);
            Bfr.q[2] = 0u; Bfr.q[3] = 0u;

            const f32x4 D = __builtin_amdgcn_mfma_f32_16x16x32_f16(Afr.v, Bfr.v, zero4, 0, 0, 0);
            // D reg r, lane p16 (g==0) = out[m=p16][c=r]

            if (g == 0 && b < nBatch) {
                float* dst = out + (size_t)b * 48 + p16 * 3;
                dst[0] = D[0]; dst[1] = D[1]; dst[2] = D[2];
            }
        }
    }
}

extern "C" void kernel_launch(void* const* d_in, const int* in_sizes, int n_in,
                              void* d_out, int out_size, void* d_ws, size_t ws_size,
                              hipStream_t stream) {
    const float* prob = (const float*)d_in[0];
    const float* W1   = (const float*)d_in[1];
    const float* b1   = (const float*)d_in[2];
    const float* W2   = (const float*)d_in[3];
    const float* b2   = (const float*)d_in[4];
    float* out        = (float*)d_out;

    const int nBatch = in_sizes[0] / 48;                    // [B,16,3]
    const int totalWaves = GRID * (BLOCK / 64);
    const int bpw = (nBatch + totalWaves - 1) / totalWaves; // 8 at B=65536

    postpro_kernel<<<GRID, BLOCK, 0, stream>>>(prob, W1, b1, W2, b2, out, nBatch, bpw);
}

// Round 11
// 167.703 us; speedup vs baseline: 2.5573x; 2.5573x over previous
//
#include <hip/hip_runtime.h>
#include <cstdint>
#include <cstddef>

typedef __attribute__((ext_vector_type(4))) float f32x4;
typedef __attribute__((ext_vector_type(2))) float f32x2;
typedef _Float16 h16x8 __attribute__((ext_vector_type(8)));

#define BLOCK 256
#define GRID  4096
#define NB    4

__device__ __forceinline__ uint32_t pk16(float a, float b) {
    // lo half = cvt(a), hi half = cvt(b), round-toward-zero
    return __builtin_bit_cast(uint32_t, __builtin_amdgcn_cvt_pkrtz(a, b));
}

// 8 consecutive floats from LDS as 4 f32x2 pairs (two b128 reads)
struct R2 { f32x2 p[4]; };
__device__ __forceinline__ R2 ld2(const float* base) {
    const f32x4 a = *(const f32x4*)base;
    const f32x4 b = *(const f32x4*)(base + 4);
    R2 r;
    r.p[0] = __builtin_shufflevector(a, a, 0, 1);
    r.p[1] = __builtin_shufflevector(a, a, 2, 3);
    r.p[2] = __builtin_shufflevector(b, b, 0, 1);
    r.p[3] = __builtin_shufflevector(b, b, 2, 3);
    return r;
}

// Lane l: p16 = l&15, g = l>>4. Element->feature convention for every MFMA
// operand: element j of chunk s <-> k = 32s + 8g + j (round-3/5/9-verified mirror).
__global__ __launch_bounds__(BLOCK, 4) void postpro_kernel(
    const float* __restrict__ prob,
    const float* __restrict__ W1,
    const float* __restrict__ b1,
    const float* __restrict__ W2,
    const float* __restrict__ b2,
    float* __restrict__ out,
    int nBatch, int bpw)
{
    __shared__ float sw[640];    // [0:512) W1 rows 0..3, [512:640) b1
    __shared__ float sW2[384];   // W2 [128][3] row-major, staged for fragment build
    const int tid = threadIdx.x;
    for (int i = tid; i < 512; i += BLOCK) sw[i] = W1[i];
    for (int i = tid; i < 128; i += BLOCK) sw[512 + i] = b1[i];
    for (int i = tid; i < 384; i += BLOCK) sW2[i] = W2[i];

    const int lane = tid & 63;
    const int p16  = lane & 15;
    const int g    = lane >> 4;

    const int wave = blockIdx.x * (BLOCK / 64) + (tid >> 6);
    const int b0   = wave * bpw;

    // group-0 prob loads issued before the barrier (no LDS dependency)
    float p0[NB], p1[NB], p2[NB];
    #pragma unroll
    for (int u = 0; u < NB; ++u) {
        int b = b0 + u; if (b > nBatch - 1) b = nBatch - 1;
        const float* pp = prob + (size_t)b * 48 + p16 * 3;
        p0[u] = pp[0]; p1[u] = pp[1]; p2[u] = pp[2];
    }

    __syncthreads();   // LDS ready

    // W2 B-frags (fp16) from LDS: element j of chunk s = W2[32s+8g+j][c=p16], 0 for c>=3
    h16x8 w2f[4];
    #pragma unroll
    for (int s = 0; s < 4; ++s) {
        union { h16x8 v; _Float16 h[8]; } pk;
        #pragma unroll
        for (int j = 0; j < 8; ++j) {
            const int k = 32 * s + 8 * g + j;
            pk.h[j] = (p16 < 3) ? (_Float16)sW2[k * 3 + p16] : (_Float16)0.0f;
        }
        w2f[s] = pk.v;
    }
    const float binit = (p16 < 3) ? b2[p16] : 0.0f;   // b2 fold: sum(attn)=1
    const f32x4 yinit = {binit, binit, binit, binit};
    const f32x4 zero4 = {0.f, 0.f, 0.f, 0.f};
    const f32x2 fn2   = {(float)p16, (float)p16};
    const f32x2 z2    = {0.f, 0.f};

    #pragma unroll 1
    for (int bi = 0; bi < bpw; bi += NB) {
        const int bb = b0 + bi;

        if (bi != 0) {
            #pragma unroll
            for (int u = 0; u < NB; ++u) {
                int b = bb + u; if (b > nBatch - 1) b = nBatch - 1;
                const float* pp = prob + (size_t)b * 48 + p16 * 3;
                p0[u] = pp[0]; p1[u] = pp[1]; p2[u] = pp[2];
            }
        }

        // packed splats
        f32x2 p0v[NB], p1v[NB], p2v[NB];
        #pragma unroll
        for (int u = 0; u < NB; ++u) {
            p0v[u] = (f32x2){p0[u], p0[u]};
            p1v[u] = (f32x2){p1[u], p1[u]};
            p2v[u] = (f32x2){p2[u], p2[u]};
        }

        f32x4 accS[NB], accY[NB];
        #pragma unroll
        for (int u = 0; u < NB; ++u) { accS[u] = zero4; accY[u] = yinit; }

        #pragma unroll
        for (int s = 0; s < 4; ++s) {
            const int h0 = 32 * s + 8 * g;
            const R2 r0  = ld2(sw + h0);
            const R2 r1  = ld2(sw + 128 + h0);
            const R2 r2  = ld2(sw + 256 + h0);
            const R2 w3  = ld2(sw + 384 + h0);
            const R2 bb1 = ld2(sw + 512 + h0);

            f32x2 basep[4];
            #pragma unroll
            for (int t = 0; t < 4; ++t)
                basep[t] = __builtin_elementwise_fma(fn2, w3.p[t], bb1.p[t]);  // batch-invariant

            #pragma unroll
            for (int u = 0; u < NB; ++u) {
                union { h16x8 v; uint32_t q[4]; } Hf;
                #pragma unroll
                for (int t = 0; t < 4; ++t) {
                    f32x2 h = __builtin_elementwise_fma(p0v[u], r0.p[t], basep[t]);
                    h = __builtin_elementwise_fma(p1v[u], r1.p[t], h);
                    h = __builtin_elementwise_fma(p2v[u], r2.p[t], h);
                    h = __builtin_elementwise_max(h, z2);
                    Hf.q[t] = pk16(h[0], h[1]);
                }
                accS[u] = __builtin_amdgcn_mfma_f32_16x16x32_f16(Hf.v, Hf.v,   accS[u], 0, 0, 0);
                accY[u] = __builtin_amdgcn_mfma_f32_16x16x32_f16(Hf.v, w2f[s], accY[u], 0, 0, 0);
            }
        }

        #pragma unroll
        for (int u = 0; u < NB; ++u) {
            const int b = bb + u;
            // transposed softmax: accS[u][r] = S[4g+r][p16] = S[p16][4g+r] (symmetric)
            float m0 = fmaxf(fmaxf(accS[u][0], accS[u][1]), fmaxf(accS[u][2], accS[u][3]));
            m0 = fmaxf(m0, __shfl_xor(m0, 16));
            m0 = fmaxf(m0, __shfl_xor(m0, 32));
            const float e0 = __expf(accS[u][0] - m0);
            const float e1 = __expf(accS[u][1] - m0);
            const float e2 = __expf(accS[u][2] - m0);
            const float e3 = __expf(accS[u][3] - m0);
            float sm = (e0 + e1) + (e2 + e3);
            sm += __shfl_xor(sm, 16);
            sm += __shfl_xor(sm, 32);
            const float inv = __builtin_amdgcn_rcpf(sm);

            // epilogue: D[c][m] = sum_k Y'^T[c][k] attn^T[k][m], K=16 logical.
            union { h16x8 v; uint32_t q[4]; } Afr, Bfr;
            Afr.q[0] = pk16(accY[u][0], accY[u][1]);
            Afr.q[1] = pk16(accY[u][2], accY[u][3]);
            Afr.q[2] = 0u; Afr.q[3] = 0u;
            Bfr.q[0] = pk16(e0 * inv, e1 * inv);
            Bfr.q[1] = pk16(e2 * inv, e3 * inv);
            Bfr.q[2] = 0u; Bfr.q[3] = 0u;

            const f32x4 D = __builtin_amdgcn_mfma_f32_16x16x32_f16(Afr.v, Bfr.v, zero4, 0, 0, 0);
            // D reg r, lane p16 (g==0) = out[m=p16][c=r]

            if (g == 0 && b < nBatch) {
                float* dst = out + (size_t)b * 48 + p16 * 3;
                dst[0] = D[0]; dst[1] = D[1]; dst[2] = D[2];
            }
        }
    }
}

extern "C" void kernel_launch(void* const* d_in, const int* in_sizes, int n_in,
                              void* d_out, int out_size, void* d_ws, size_t ws_size,
                              hipStream_t stream) {
    const float* prob = (const float*)d_in[0];
    const float* W1   = (const float*)d_in[1];
    const float* b1   = (const float*)d_in[2];
    const float* W2   = (const float*)d_in[3];
    const float* b2   = (const float*)d_in[4];
    float* out        = (float*)d_out;

    const int nBatch = in_sizes[0] / 48;                    // [B,16,3]
    const int totalWaves = GRID * (BLOCK / 64);
    const int bpw = (nBatch + totalWaves - 1) / totalWaves; // 4 at B=65536

    postpro_kernel<<<GRID, BLOCK, 0, stream>>>(prob, W1, b1, W2, b2, out, nBatch, bpw);
}

// Round 12
// 35.175 us; speedup vs baseline: 12.1924x; 4.7677x over previous
//
#include <hip/hip_runtime.h>
#include <cstdint>
#include <cstddef>

typedef __attribute__((ext_vector_type(4))) float f32x4;
typedef _Float16 h16x8 __attribute__((ext_vector_type(8)));

#define BLOCK 256
#define GRID  2048
#define NB    8

__device__ __forceinline__ uint32_t pk16(float a, float b) {
    // lo half = cvt(a), hi half = cvt(b), round-toward-zero
    return __builtin_bit_cast(uint32_t, __builtin_amdgcn_cvt_pkrtz(a, b));
}

// Lane l: p16 = l&15, g = l>>4. Element->feature convention for every MFMA
// operand: element j of chunk s <-> k = 32s + 8g + j (round-3/5/9-verified mirror).
// NB=8: one batch-group per wave (2048 blocks x 4 waves x 8 = 65536), max ILP.
// launch_bounds(256,3): VGPR cap ~168 -- NB=8 needs ~145 live, (256,4)'s 128 would spill.
__global__ __launch_bounds__(BLOCK, 3) void postpro_kernel(
    const float* __restrict__ prob,
    const float* __restrict__ W1,
    const float* __restrict__ b1,
    const float* __restrict__ W2,
    const float* __restrict__ b2,
    float* __restrict__ out,
    int nBatch)
{
    __shared__ float sw[640];    // [0:512) W1 rows 0..3, [512:640) b1
    __shared__ float sW2[384];   // W2 [128][3] row-major (proven r10/r11)
    const int tid = threadIdx.x;
    for (int i = tid; i < 512; i += BLOCK) sw[i] = W1[i];
    for (int i = tid; i < 128; i += BLOCK) sw[512 + i] = b1[i];
    for (int i = tid; i < 384; i += BLOCK) sW2[i] = W2[i];

    const int lane = tid & 63;
    const int p16  = lane & 15;
    const int g    = lane >> 4;
    const float fn = (float)p16;

    const int wave = blockIdx.x * (BLOCK / 64) + (tid >> 6);
    const int b0   = wave * NB;

    // all prob loads hoisted before the barrier (no LDS dependency)
    float p0[NB], p1[NB], p2[NB];
    #pragma unroll
    for (int u = 0; u < NB; ++u) {
        int b = b0 + u; if (b > nBatch - 1) b = nBatch - 1;
        const float* pp = prob + (size_t)b * 48 + p16 * 3;
        p0[u] = pp[0]; p1[u] = pp[1]; p2[u] = pp[2];
    }

    __syncthreads();   // LDS ready

    // W2 B-frags (fp16) from LDS: element j of chunk s = W2[32s+8g+j][c=p16], 0 for c>=3
    h16x8 w2f[4];
    #pragma unroll
    for (int s = 0; s < 4; ++s) {
        union { h16x8 v; _Float16 h[8]; } pk;
        #pragma unroll
        for (int j = 0; j < 8; ++j) {
            const int k = 32 * s + 8 * g + j;
            pk.h[j] = (p16 < 3) ? (_Float16)sW2[k * 3 + p16] : (_Float16)0.0f;
        }
        w2f[s] = pk.v;
    }
    const float binit = (p16 < 3) ? b2[p16] : 0.0f;   // b2 fold: sum(attn)=1
    const f32x4 yinit = {binit, binit, binit, binit};
    const f32x4 zero4 = {0.f, 0.f, 0.f, 0.f};

    f32x4 accS[NB], accY[NB];
    #pragma unroll
    for (int u = 0; u < NB; ++u) { accS[u] = zero4; accY[u] = yinit; }

    #pragma unroll
    for (int s = 0; s < 4; ++s) {
        const int h0 = 32 * s + 8 * g;
        const f32x4 r0a = *(const f32x4*)(sw + h0);
        const f32x4 r0b = *(const f32x4*)(sw + h0 + 4);
        const f32x4 r1a = *(const f32x4*)(sw + 128 + h0);
        const f32x4 r1b = *(const f32x4*)(sw + 128 + h0 + 4);
        const f32x4 r2a = *(const f32x4*)(sw + 256 + h0);
        const f32x4 r2b = *(const f32x4*)(sw + 256 + h0 + 4);
        const f32x4 w3a = *(const f32x4*)(sw + 384 + h0);
        const f32x4 w3b = *(const f32x4*)(sw + 384 + h0 + 4);
        const f32x4 b1a = *(const f32x4*)(sw + 512 + h0);
        const f32x4 b1b = *(const f32x4*)(sw + 512 + h0 + 4);

        float r0_[8], r1_[8], r2_[8], base_[8];
        #pragma unroll
        for (int j = 0; j < 4; ++j) {
            r0_[j] = r0a[j]; r0_[4 + j] = r0b[j];
            r1_[j] = r1a[j]; r1_[4 + j] = r1b[j];
            r2_[j] = r2a[j]; r2_[4 + j] = r2b[j];
            base_[j]     = fmaf(fn, w3a[j], b1a[j]);   // batch-invariant
            base_[4 + j] = fmaf(fn, w3b[j], b1b[j]);
        }

        #pragma unroll
        for (int u = 0; u < NB; ++u) {
            float H[8];
            #pragma unroll
            for (int j = 0; j < 8; ++j) {
                float h = fmaf(p0[u], r0_[j], base_[j]);
                h = fmaf(p1[u], r1_[j], h);
                h = fmaf(p2[u], r2_[j], h);
                H[j] = fmaxf(h, 0.0f);
            }
            union { h16x8 v; uint32_t q[4]; } Hf;
            #pragma unroll
            for (int t = 0; t < 4; ++t) Hf.q[t] = pk16(H[2 * t], H[2 * t + 1]);

            accS[u] = __builtin_amdgcn_mfma_f32_16x16x32_f16(Hf.v, Hf.v,   accS[u], 0, 0, 0);
            accY[u] = __builtin_amdgcn_mfma_f32_16x16x32_f16(Hf.v, w2f[s], accY[u], 0, 0, 0);
        }
    }

    #pragma unroll
    for (int u = 0; u < NB; ++u) {
        const int b = b0 + u;
        // transposed softmax: accS[u][r] = S[4g+r][p16] = S[p16][4g+r] (symmetric)
        float m0 = fmaxf(fmaxf(accS[u][0], accS[u][1]), fmaxf(accS[u][2], accS[u][3]));
        m0 = fmaxf(m0, __shfl_xor(m0, 16));
        m0 = fmaxf(m0, __shfl_xor(m0, 32));
        const float e0 = __expf(accS[u][0] - m0);
        const float e1 = __expf(accS[u][1] - m0);
        const float e2 = __expf(accS[u][2] - m0);
        const float e3 = __expf(accS[u][3] - m0);
        float sm = (e0 + e1) + (e2 + e3);
        sm += __shfl_xor(sm, 16);
        sm += __shfl_xor(sm, 32);
        const float inv = __builtin_amdgcn_rcpf(sm);

        // epilogue: D[c][m] = sum_k Y'^T[c][k] attn^T[k][m], K=16 logical.
        union { h16x8 v; uint32_t q[4]; } Afr, Bfr;
        Afr.q[0] = pk16(accY[u][0], accY[u][1]);
        Afr.q[1] = pk16(accY[u][2], accY[u][3]);
        Afr.q[2] = 0u; Afr.q[3] = 0u;
        Bfr.q[0] = pk16(e0 * inv, e1 * inv);
        Bfr.q[1] = pk16(e2 * inv, e3 * inv);
        Bfr.q[2] = 0u; Bfr.q[3] = 0u;

        const f32x4 D = __builtin_amdgcn_mfma_f32_16x16x32_f16(Afr.v, Bfr.v, zero4, 0, 0, 0);
        // D reg r, lane p16 (g==0) = out[m=p16][c=r]

        if (g == 0 && b < nBatch) {
            float* dst = out + (size_t)b * 48 + p16 * 3;
            dst[0] = D[0]; dst[1] = D[1]; dst[2] = D[2];
        }
    }
}

extern "C" void kernel_launch(void* const* d_in, const int* in_sizes, int n_in,
                              void* d_out, int out_size, void* d_ws, size_t ws_size,
                              hipStream_t stream) {
    const float* prob = (const float*)d_in[0];
    const float* W1   = (const float*)d_in[1];
    const float* b1   = (const float*)d_in[2];
    const float* W2   = (const float*)d_in[3];
    const float* b2   = (const float*)d_in[4];
    float* out        = (float*)d_out;

    const int nBatch = in_sizes[0] / 48;   // [B,16,3] -> 65536
    // GRID*4 waves * NB batches = 65536 exactly at B=65536; clamps handle other B
    postpro_kernel<<<GRID, BLOCK, 0, stream>>>(prob, W1, b1, W2, b2, out, nBatch);
}

// Round 13
// 33.476 us; speedup vs baseline: 12.8111x; 1.0507x over previous
//
#include <hip/hip_runtime.h>
#include <cstdint>
#include <cstddef>

typedef __attribute__((ext_vector_type(4))) float f32x4;
typedef _Float16 h16x8 __attribute__((ext_vector_type(8)));

#define BLOCK 256
#define GRID  2048
#define NB    8

__device__ __forceinline__ uint32_t pk16(float a, float b) {
    // lo half = cvt(a), hi half = cvt(b), round-toward-zero
    return __builtin_bit_cast(uint32_t, __builtin_amdgcn_cvt_pkrtz(a, b));
}

union H8 { h16x8 v; uint32_t q[4]; };

// Lane l: p16 = l&15, g = l>>4.
// H computed by MFMA: D = W1aug^T (A) x xaug^T (B), K=5 logical (k=0..2: probs,
// k=3: member idx, k=4: bias one-hot). Output: lane p16 reg r of tile T holds
// H[member p16][h = 16T + 4g + r]  ->  per-lane h-map for Gram/Y chunks:
//   chunk s slot j <-> h = 32s + 16*(j>>2) + 4g + (j&3)   (mu)
// Gram is mu-invariant (A=B, mirror verified r1/r3); w2f is built with the same mu.
__global__ __launch_bounds__(BLOCK, 2) void postpro_kernel(
    const float* __restrict__ prob,
    const float* __restrict__ W1,
    const float* __restrict__ b1,
    const float* __restrict__ W2,
    const float* __restrict__ b2,
    float* __restrict__ out,
    int nBatch)
{
    __shared__ float sw[640];    // [0:512) W1 rows 0..3, [512:640) b1
    __shared__ float sW2[384];   // W2 [128][3] row-major
    const int tid = threadIdx.x;
    for (int i = tid; i < 512; i += BLOCK) sw[i] = W1[i];
    for (int i = tid; i < 128; i += BLOCK) sw[512 + i] = b1[i];
    for (int i = tid; i < 384; i += BLOCK) sW2[i] = W2[i];

    const int lane = tid & 63;
    const int p16  = lane & 15;
    const int g    = lane >> 4;
    const float fn = (float)p16;
    const bool g0  = (g == 0);

    const int wave = blockIdx.x * (BLOCK / 64) + (tid >> 6);
    const int b0   = wave * NB;

    // prob loads + xaug B-frags (pre-barrier; no LDS dependency)
    // B[k][m=p16], k=0..4 = {p0,p1,p2,fn,1}; slots j=k for g=0, zero elsewhere.
    H8 xf[NB];
    #pragma unroll
    for (int u = 0; u < NB; ++u) {
        int b = b0 + u; if (b > nBatch - 1) b = nBatch - 1;
        const float* pp = prob + (size_t)b * 48 + p16 * 3;
        const float p0 = pp[0], p1 = pp[1], p2 = pp[2];
        xf[u].q[0] = g0 ? pk16(p0, p1) : 0u;
        xf[u].q[1] = g0 ? pk16(p2, fn) : 0u;
        xf[u].q[2] = g0 ? 0x00003C00u : 0u;   // (1.0h, 0)
        xf[u].q[3] = 0u;
    }

    __syncthreads();   // LDS ready

    // W1aug A-frags (batch-invariant): tile T, lane p16 -> row h = 16T + p16,
    // slots j=k (g=0): {W1[0][h],W1[1][h],W1[2][h],W1[3][h],b1[h],0,0,0}
    H8 wf[8];
    #pragma unroll
    for (int T = 0; T < 8; ++T) {
        const int h = 16 * T + p16;
        wf[T].q[0] = g0 ? pk16(sw[h],       sw[128 + h]) : 0u;
        wf[T].q[1] = g0 ? pk16(sw[256 + h], sw[384 + h]) : 0u;
        wf[T].q[2] = g0 ? pk16(sw[512 + h], 0.0f)        : 0u;
        wf[T].q[3] = 0u;
    }

    // W2 B-frags with the mu h-map: chunk s slot j -> h = 32s + 16*(j>>2) + 4g + (j&3)
    const bool cc = (p16 < 3);
    H8 w2f[4];
    #pragma unroll
    for (int s = 0; s < 4; ++s) {
        const int hb = 32 * s + 4 * g;
        w2f[s].q[0] = cc ? pk16(sW2[(hb +  0) * 3 + p16], sW2[(hb +  1) * 3 + p16]) : 0u;
        w2f[s].q[1] = cc ? pk16(sW2[(hb +  2) * 3 + p16], sW2[(hb +  3) * 3 + p16]) : 0u;
        w2f[s].q[2] = cc ? pk16(sW2[(hb + 16) * 3 + p16], sW2[(hb + 17) * 3 + p16]) : 0u;
        w2f[s].q[3] = cc ? pk16(sW2[(hb + 18) * 3 + p16], sW2[(hb + 19) * 3 + p16]) : 0u;
    }

    const float binit = cc ? b2[p16] : 0.0f;   // b2 fold: sum(attn)=1
    const f32x4 yinit = {binit, binit, binit, binit};
    const f32x4 zero4 = {0.f, 0.f, 0.f, 0.f};

    #pragma unroll
    for (int u = 0; u < NB; ++u) {
        // H tiles on the matrix pipe (8 independent MFMAs, K=5 useful)
        f32x4 hD[8];
        #pragma unroll
        for (int T = 0; T < 8; ++T)
            hD[T] = __builtin_amdgcn_mfma_f32_16x16x32_f16(wf[T].v, xf[u].v, zero4, 0, 0, 0);

        f32x4 accS = zero4, accY = yinit;
        #pragma unroll
        for (int s = 0; s < 4; ++s) {
            const f32x4 d0 = hD[2 * s], d1 = hD[2 * s + 1];
            H8 Hf;   // relu + pack per mu: q0/q1 <- tile 2s, q2/q3 <- tile 2s+1
            Hf.q[0] = pk16(fmaxf(d0[0], 0.f), fmaxf(d0[1], 0.f));
            Hf.q[1] = pk16(fmaxf(d0[2], 0.f), fmaxf(d0[3], 0.f));
            Hf.q[2] = pk16(fmaxf(d1[0], 0.f), fmaxf(d1[1], 0.f));
            Hf.q[3] = pk16(fmaxf(d1[2], 0.f), fmaxf(d1[3], 0.f));

            accS = __builtin_amdgcn_mfma_f32_16x16x32_f16(Hf.v, Hf.v,     accS, 0, 0, 0);
            accY = __builtin_amdgcn_mfma_f32_16x16x32_f16(Hf.v, w2f[s].v, accY, 0, 0, 0);
        }

        // transposed softmax: accS[r] = S[4g+r][p16] = S[p16][4g+r] (symmetric)
        float m0 = fmaxf(fmaxf(accS[0], accS[1]), fmaxf(accS[2], accS[3]));
        m0 = fmaxf(m0, __shfl_xor(m0, 16));
        m0 = fmaxf(m0, __shfl_xor(m0, 32));
        const float e0 = __expf(accS[0] - m0);
        const float e1 = __expf(accS[1] - m0);
        const float e2 = __expf(accS[2] - m0);
        const float e3 = __expf(accS[3] - m0);
        float sm = (e0 + e1) + (e2 + e3);
        sm += __shfl_xor(sm, 16);
        sm += __shfl_xor(sm, 32);
        const float inv = __builtin_amdgcn_rcpf(sm);

        // epilogue: D[c][m] = sum_k Y'^T[c][k] attn^T[k][m], K=16 logical
        H8 Afr, Bfr;
        Afr.q[0] = pk16(accY[0], accY[1]);
        Afr.q[1] = pk16(accY[2], accY[3]);
        Afr.q[2] = 0u; Afr.q[3] = 0u;
        Bfr.q[0] = pk16(e0 * inv, e1 * inv);
        Bfr.q[1] = pk16(e2 * inv, e3 * inv);
        Bfr.q[2] = 0u; Bfr.q[3] = 0u;

        const f32x4 D = __builtin_amdgcn_mfma_f32_16x16x32_f16(Afr.v, Bfr.v, zero4, 0, 0, 0);
        // D reg r, lane p16 (g==0) = out[m=p16][c=r]

        const int b = b0 + u;
        if (g0 && b < nBatch) {
            float* dst = out + (size_t)b * 48 + p16 * 3;
            dst[0] = D[0]; dst[1] = D[1]; dst[2] = D[2];
        }
    }
}

extern "C" void kernel_launch(void* const* d_in, const int* in_sizes, int n_in,
                              void* d_out, int out_size, void* d_ws, size_t ws_size,
                              hipStream_t stream) {
    const float* prob = (const float*)d_in[0];
    const float* W1   = (const float*)d_in[1];
    const float* b1   = (const float*)d_in[2];
    const float* W2   = (const float*)d_in[3];
    const float* b2   = (const float*)d_in[4];
    float* out        = (float*)d_out;

    const int nBatch = in_sizes[0] / 48;   // [B,16,3] -> 65536
    // GRID * 4 waves * NB = 65536 exactly at B=65536; clamps handle other B
    postpro_kernel<<<GRID, BLOCK, 0, stream>>>(prob, W1, b1, W2, b2, out, nBatch);
}

// Round 14
// 33.082 us; speedup vs baseline: 12.9637x; 1.0119x over previous
//
#include <hip/hip_runtime.h>
#include <cstdint>
#include <cstddef>

typedef __attribute__((ext_vector_type(4))) float f32x4;
typedef _Float16 h16x8 __attribute__((ext_vector_type(8)));

#define BLOCK 256
#define GRID  512
#define NB    8

__device__ __forceinline__ uint32_t pk16(float a, float b) {
    // lo half = cvt(a), hi half = cvt(b), round-toward-zero
    return __builtin_bit_cast(uint32_t, __builtin_amdgcn_cvt_pkrtz(a, b));
}

union H8 { h16x8 v; uint32_t q[4]; };

// Lane l: p16 = l&15, g = l>>4.  Persistent waves: setup (LDS + wf/w2f frags)
// once, then a barrier-free grid-stride loop over batch-groups with next-group
// prob loads prefetched under the current group's compute.
// Compute body identical to r13 (proven): H via MFMA (K=5), mu h-map
// chunk s slot j <-> h = 32s + 16*(j>>2) + 4g + (j&3) on Gram/Y/W2 frags.
__global__ __launch_bounds__(BLOCK, 2) void postpro_kernel(
    const float* __restrict__ prob,
    const float* __restrict__ W1,
    const float* __restrict__ b1,
    const float* __restrict__ W2,
    const float* __restrict__ b2,
    float* __restrict__ out,
    int nBatch, int nGroups)
{
    __shared__ float sw[640];    // [0:512) W1 rows 0..3, [512:640) b1
    __shared__ float sW2[384];   // W2 [128][3] row-major
    const int tid = threadIdx.x;
    for (int i = tid; i < 512; i += BLOCK) sw[i] = W1[i];
    for (int i = tid; i < 128; i += BLOCK) sw[512 + i] = b1[i];
    for (int i = tid; i < 384; i += BLOCK) sW2[i] = W2[i];

    const int lane = tid & 63;
    const int p16  = lane & 15;
    const int g    = lane >> 4;
    const float fn = (float)p16;
    const bool g0  = (g == 0);

    const int wave   = blockIdx.x * (BLOCK / 64) + (tid >> 6);
    const int nWaves = GRID * (BLOCK / 64);   // 2048

    // group-0 prob loads issued pre-barrier (no LDS dependency)
    float pc0[NB], pc1[NB], pc2[NB];
    #pragma unroll
    for (int u = 0; u < NB; ++u) {
        int b = wave * NB + u; if (b > nBatch - 1) b = nBatch - 1;
        const float* pp = prob + (size_t)b * 48 + p16 * 3;
        pc0[u] = pp[0]; pc1[u] = pp[1]; pc2[u] = pp[2];
    }

    __syncthreads();   // LDS ready (the only barrier in the kernel)

    // W1aug A-frags (once per wave): tile T, lane p16 -> row h = 16T + p16
    H8 wf[8];
    #pragma unroll
    for (int T = 0; T < 8; ++T) {
        const int h = 16 * T + p16;
        wf[T].q[0] = g0 ? pk16(sw[h],       sw[128 + h]) : 0u;
        wf[T].q[1] = g0 ? pk16(sw[256 + h], sw[384 + h]) : 0u;
        wf[T].q[2] = g0 ? pk16(sw[512 + h], 0.0f)        : 0u;
        wf[T].q[3] = 0u;
    }
    // W2 B-frags with the mu h-map
    const bool cc = (p16 < 3);
    H8 w2f[4];
    #pragma unroll
    for (int s = 0; s < 4; ++s) {
        const int hb = 32 * s + 4 * g;
        w2f[s].q[0] = cc ? pk16(sW2[(hb +  0) * 3 + p16], sW2[(hb +  1) * 3 + p16]) : 0u;
        w2f[s].q[1] = cc ? pk16(sW2[(hb +  2) * 3 + p16], sW2[(hb +  3) * 3 + p16]) : 0u;
        w2f[s].q[2] = cc ? pk16(sW2[(hb + 16) * 3 + p16], sW2[(hb + 17) * 3 + p16]) : 0u;
        w2f[s].q[3] = cc ? pk16(sW2[(hb + 18) * 3 + p16], sW2[(hb + 19) * 3 + p16]) : 0u;
    }
    const float binit = cc ? b2[p16] : 0.0f;   // b2 fold: sum(attn)=1
    const f32x4 yinit = {binit, binit, binit, binit};
    const f32x4 zero4 = {0.f, 0.f, 0.f, 0.f};

    #pragma unroll 1
    for (int k = 0; k < nGroups; ++k) {
        const int G = wave + k * nWaves;

        // pack current group's xaug B-frags
        H8 xf[NB];
        #pragma unroll
        for (int u = 0; u < NB; ++u) {
            xf[u].q[0] = g0 ? pk16(pc0[u], pc1[u]) : 0u;
            xf[u].q[1] = g0 ? pk16(pc2[u], fn) : 0u;
            xf[u].q[2] = g0 ? 0x00003C00u : 0u;   // (1.0h, 0)
            xf[u].q[3] = 0u;
        }

        // prefetch next group's probs — returns under this group's compute
        float pn0[NB], pn1[NB], pn2[NB];
        const bool more = (k + 1 < nGroups);
        if (more) {
            const int Gn = wave + (k + 1) * nWaves;
            #pragma unroll
            for (int u = 0; u < NB; ++u) {
                int b = Gn * NB + u; if (b > nBatch - 1) b = nBatch - 1;
                const float* pp = prob + (size_t)b * 48 + p16 * 3;
                pn0[u] = pp[0]; pn1[u] = pp[1]; pn2[u] = pp[2];
            }
        }

        #pragma unroll
        for (int u = 0; u < NB; ++u) {
            // H tiles on the matrix pipe (8 independent MFMAs, K=5 useful)
            f32x4 hD[8];
            #pragma unroll
            for (int T = 0; T < 8; ++T)
                hD[T] = __builtin_amdgcn_mfma_f32_16x16x32_f16(wf[T].v, xf[u].v, zero4, 0, 0, 0);

            f32x4 accS = zero4, accY = yinit;
            #pragma unroll
            for (int s = 0; s < 4; ++s) {
                const f32x4 d0 = hD[2 * s], d1 = hD[2 * s + 1];
                H8 Hf;   // relu + pack per mu
                Hf.q[0] = pk16(fmaxf(d0[0], 0.f), fmaxf(d0[1], 0.f));
                Hf.q[1] = pk16(fmaxf(d0[2], 0.f), fmaxf(d0[3], 0.f));
                Hf.q[2] = pk16(fmaxf(d1[0], 0.f), fmaxf(d1[1], 0.f));
                Hf.q[3] = pk16(fmaxf(d1[2], 0.f), fmaxf(d1[3], 0.f));

                accS = __builtin_amdgcn_mfma_f32_16x16x32_f16(Hf.v, Hf.v,     accS, 0, 0, 0);
                accY = __builtin_amdgcn_mfma_f32_16x16x32_f16(Hf.v, w2f[s].v, accY, 0, 0, 0);
            }

            // transposed softmax: accS[r] = S[4g+r][p16] = S[p16][4g+r] (symmetric)
            float m0 = fmaxf(fmaxf(accS[0], accS[1]), fmaxf(accS[2], accS[3]));
            m0 = fmaxf(m0, __shfl_xor(m0, 16));
            m0 = fmaxf(m0, __shfl_xor(m0, 32));
            const float e0 = __expf(accS[0] - m0);
            const float e1 = __expf(accS[1] - m0);
            const float e2 = __expf(accS[2] - m0);
            const float e3 = __expf(accS[3] - m0);
            float sm = (e0 + e1) + (e2 + e3);
            sm += __shfl_xor(sm, 16);
            sm += __shfl_xor(sm, 32);
            const float inv = __builtin_amdgcn_rcpf(sm);

            // epilogue: D[c][m] = sum_k Y'^T[c][k] attn^T[k][m]
            H8 Afr, Bfr;
            Afr.q[0] = pk16(accY[0], accY[1]);
            Afr.q[1] = pk16(accY[2], accY[3]);
            Afr.q[2] = 0u; Afr.q[3] = 0u;
            Bfr.q[0] = pk16(e0 * inv, e1 * inv);
            Bfr.q[1] = pk16(e2 * inv, e3 * inv);
            Bfr.q[2] = 0u; Bfr.q[3] = 0u;

            const f32x4 D = __builtin_amdgcn_mfma_f32_16x16x32_f16(Afr.v, Bfr.v, zero4, 0, 0, 0);
            // D reg r, lane p16 (g==0) = out[m=p16][c=r]

            const int b = G * NB + u;
            if (g0 && b < nBatch) {
                float* dst = out + (size_t)b * 48 + p16 * 3;
                dst[0] = D[0]; dst[1] = D[1]; dst[2] = D[2];
            }
        }

        // rotate prefetch buffers
        if (more) {
            #pragma unroll
            for (int u = 0; u < NB; ++u) {
                pc0[u] = pn0[u]; pc1[u] = pn1[u]; pc2[u] = pn2[u];
            }
        }
    }
}

extern "C" void kernel_launch(void* const* d_in, const int* in_sizes, int n_in,
                              void* d_out, int out_size, void* d_ws, size_t ws_size,
                              hipStream_t stream) {
    const float* prob = (const float*)d_in[0];
    const float* W1   = (const float*)d_in[1];
    const float* b1   = (const float*)d_in[2];
    const float* W2   = (const float*)d_in[3];
    const float* b2   = (const float*)d_in[4];
    float* out        = (float*)d_out;

    const int nBatch  = in_sizes[0] / 48;                    // [B,16,3] -> 65536
    const int nWaves  = GRID * (BLOCK / 64);                 // 2048
    const int nGroups = (nBatch + nWaves * NB - 1) / (nWaves * NB);   // 4 at B=65536

    postpro_kernel<<<GRID, BLOCK, 0, stream>>>(prob, W1, b1, W2, b2, out, nBatch, nGroups);
}

// Round 15
// 28.572 us; speedup vs baseline: 15.0097x; 1.1578x over previous
//
#include <hip/hip_runtime.h>
#include <cstdint>
#include <cstddef>

typedef __attribute__((ext_vector_type(4))) float f32x4;
typedef __attribute__((ext_vector_type(3))) float f32x3;
typedef _Float16 h16x8 __attribute__((ext_vector_type(8)));
typedef _Float16 h16x2v __attribute__((ext_vector_type(2)));

#define BLOCK 256
#define GRID  1024
#define NB    8

__device__ __forceinline__ uint32_t pk16(float a, float b) {
    // lo half = cvt(a), hi half = cvt(b), round-toward-zero
    return __builtin_bit_cast(uint32_t, __builtin_amdgcn_cvt_pkrtz(a, b));
}

// packed f16 relu on an already-packed pair (cvt is monotone & fixes 0, so
// relu-after-cvt == cvt-after-relu; r7/r8 bit-identical results exonerate this op)
__device__ __forceinline__ uint32_t pkmax0(uint32_t x) {
    h16x2v v = __builtin_bit_cast(h16x2v, x);
    const h16x2v z = {(_Float16)0.0f, (_Float16)0.0f};
    return __builtin_bit_cast(uint32_t, __builtin_elementwise_max(v, z));
}

union H8 { h16x8 v; uint32_t q[4]; };

// Lane l: p16 = l&15, g = l>>4.  Persistent waves (setup once), grid-stride
// over 2 groups of NB=8 with next-group prob prefetch under compute.
// H via MFMA (K=5), mu h-map chunk s slot j <-> h = 32s + 16*(j>>2) + 4g + (j&3).
// Softmax denominator via ones-row (A row c=3) in the epilogue MFMA:
// D[3][m] = sum_k e[k][m]; out = D[c] * rcp(D[3]); b2-fold survives exactly.
__global__ __launch_bounds__(BLOCK, 4) void postpro_kernel(
    const float* __restrict__ prob,
    const float* __restrict__ W1,
    const float* __restrict__ b1,
    const float* __restrict__ W2,
    const float* __restrict__ b2,
    float* __restrict__ out,
    int nBatch, int nGroups)
{
    __shared__ float sw[640];    // [0:512) W1 rows 0..3, [512:640) b1
    __shared__ float sW2[384];   // W2 [128][3] row-major
    const int tid = threadIdx.x;
    for (int i = tid; i < 512; i += BLOCK) sw[i] = W1[i];
    for (int i = tid; i < 128; i += BLOCK) sw[512 + i] = b1[i];
    for (int i = tid; i < 384; i += BLOCK) sW2[i] = W2[i];

    const int lane = tid & 63;
    const int p16  = lane & 15;
    const int g    = lane >> 4;
    const float fn = (float)p16;
    const bool g0  = (g == 0);

    const int wave   = blockIdx.x * (BLOCK / 64) + (tid >> 6);
    const int nWaves = GRID * (BLOCK / 64);   // 4096

    // group-0 prob loads issued pre-barrier (no LDS dependency)
    float pc0[NB], pc1[NB], pc2[NB];
    #pragma unroll
    for (int u = 0; u < NB; ++u) {
        int b = wave * NB + u; if (b > nBatch - 1) b = nBatch - 1;
        const float* pp = prob + (size_t)b * 48 + p16 * 3;
        pc0[u] = pp[0]; pc1[u] = pp[1]; pc2[u] = pp[2];
    }

    __syncthreads();   // LDS ready (the only barrier)

    // W1aug A-frags (once per wave): tile T, lane p16 -> row h = 16T + p16
    H8 wf[8];
    #pragma unroll
    for (int T = 0; T < 8; ++T) {
        const int h = 16 * T + p16;
        wf[T].q[0] = g0 ? pk16(sw[h],       sw[128 + h]) : 0u;
        wf[T].q[1] = g0 ? pk16(sw[256 + h], sw[384 + h]) : 0u;
        wf[T].q[2] = g0 ? pk16(sw[512 + h], 0.0f)        : 0u;
        wf[T].q[3] = 0u;
    }
    // W2 B-frags with the mu h-map
    const bool cc = (p16 < 3);
    H8 w2f[4];
    #pragma unroll
    for (int s = 0; s < 4; ++s) {
        const int hb = 32 * s + 4 * g;
        w2f[s].q[0] = cc ? pk16(sW2[(hb +  0) * 3 + p16], sW2[(hb +  1) * 3 + p16]) : 0u;
        w2f[s].q[1] = cc ? pk16(sW2[(hb +  2) * 3 + p16], sW2[(hb +  3) * 3 + p16]) : 0u;
        w2f[s].q[2] = cc ? pk16(sW2[(hb + 16) * 3 + p16], sW2[(hb + 17) * 3 + p16]) : 0u;
        w2f[s].q[3] = cc ? pk16(sW2[(hb + 18) * 3 + p16], sW2[(hb + 19) * 3 + p16]) : 0u;
    }
    const float binit = cc ? b2[p16] : 0.0f;       // b2 fold (exact through post-normalization)
    const f32x4 yinit = {binit, binit, binit, binit};
    const f32x4 zero4 = {0.f, 0.f, 0.f, 0.f};
    const uint32_t ones0 = (p16 == 3) ? 0x3C003C00u : 0u;   // epilogue ones-row (k=0..3)

    #pragma unroll 1
    for (int k = 0; k < nGroups; ++k) {
        const int G = wave + k * nWaves;

        // pack current group's xaug B-frags
        H8 xf[NB];
        #pragma unroll
        for (int u = 0; u < NB; ++u) {
            xf[u].q[0] = g0 ? pk16(pc0[u], pc1[u]) : 0u;
            xf[u].q[1] = g0 ? pk16(pc2[u], fn) : 0u;
            xf[u].q[2] = g0 ? 0x00003C00u : 0u;   // (1.0h, 0)
            xf[u].q[3] = 0u;
        }

        // prefetch next group's probs — returns under this group's compute
        float pn0[NB], pn1[NB], pn2[NB];
        const bool more = (k + 1 < nGroups);
        if (more) {
            const int Gn = wave + (k + 1) * nWaves;
            #pragma unroll
            for (int u = 0; u < NB; ++u) {
                int b = Gn * NB + u; if (b > nBatch - 1) b = nBatch - 1;
                const float* pp = prob + (size_t)b * 48 + p16 * 3;
                pn0[u] = pp[0]; pn1[u] = pp[1]; pn2[u] = pp[2];
            }
        }

        #pragma unroll
        for (int u = 0; u < NB; ++u) {
            // H tiles on the matrix pipe (8 independent MFMAs, K=5 useful)
            f32x4 hD[8];
            #pragma unroll
            for (int T = 0; T < 8; ++T)
                hD[T] = __builtin_amdgcn_mfma_f32_16x16x32_f16(wf[T].v, xf[u].v, zero4, 0, 0, 0);

            f32x4 accS = zero4, accY = yinit;
            #pragma unroll
            for (int s = 0; s < 4; ++s) {
                const f32x4 d0 = hD[2 * s], d1 = hD[2 * s + 1];
                H8 Hf;   // pack then packed-relu (v_pk_max_f16)
                Hf.q[0] = pkmax0(pk16(d0[0], d0[1]));
                Hf.q[1] = pkmax0(pk16(d0[2], d0[3]));
                Hf.q[2] = pkmax0(pk16(d1[0], d1[1]));
                Hf.q[3] = pkmax0(pk16(d1[2], d1[3]));

                accS = __builtin_amdgcn_mfma_f32_16x16x32_f16(Hf.v, Hf.v,     accS, 0, 0, 0);
                accY = __builtin_amdgcn_mfma_f32_16x16x32_f16(Hf.v, w2f[s].v, accY, 0, 0, 0);
            }

            // transposed softmax, numerator only: accS[r] = S[p16][4g+r] (symmetric)
            float m0 = fmaxf(fmaxf(accS[0], accS[1]), fmaxf(accS[2], accS[3]));
            m0 = fmaxf(m0, __shfl_xor(m0, 16));
            m0 = fmaxf(m0, __shfl_xor(m0, 32));
            const float e0 = __expf(accS[0] - m0);   // <= 1: f16-safe
            const float e1 = __expf(accS[1] - m0);
            const float e2 = __expf(accS[2] - m0);
            const float e3 = __expf(accS[3] - m0);

            // epilogue: D[c][m] = sum_k A[c][k] e[k][m]; A rows 0..2 = Y'^T, row 3 = ones
            H8 Afr, Bfr;
            Afr.q[0] = cc ? pk16(accY[0], accY[1]) : ones0;
            Afr.q[1] = cc ? pk16(accY[2], accY[3]) : ones0;
            Afr.q[2] = 0u; Afr.q[3] = 0u;
            Bfr.q[0] = pk16(e0, e1);
            Bfr.q[1] = pk16(e2, e3);
            Bfr.q[2] = 0u; Bfr.q[3] = 0u;

            const f32x4 D = __builtin_amdgcn_mfma_f32_16x16x32_f16(Afr.v, Bfr.v, zero4, 0, 0, 0);
            // D reg r, lane p16 (g==0): r=0..2 -> unnormalized out[m=p16][c=r], r=3 -> sum(e)

            const int b = G * NB + u;
            if (g0 && b < nBatch) {
                const float inv = __builtin_amdgcn_rcpf(D[3]);
                float* dst = out + (size_t)b * 48 + p16 * 3;
                f32x3 v = {D[0] * inv, D[1] * inv, D[2] * inv};
                *(f32x3*)dst = v;
            }
        }

        // rotate prefetch buffers
        if (more) {
            #pragma unroll
            for (int u = 0; u < NB; ++u) {
                pc0[u] = pn0[u]; pc1[u] = pn1[u]; pc2[u] = pn2[u];
            }
        }
    }
}

extern "C" void kernel_launch(void* const* d_in, const int* in_sizes, int n_in,
                              void* d_out, int out_size, void* d_ws, size_t ws_size,
                              hipStream_t stream) {
    const float* prob = (const float*)d_in[0];
    const float* W1   = (const float*)d_in[1];
    const float* b1   = (const float*)d_in[2];
    const float* W2   = (const float*)d_in[3];
    const float* b2   = (const float*)d_in[4];
    float* out        = (float*)d_out;

    const int nBatch  = in_sizes[0] / 48;                    // [B,16,3] -> 65536
    const int nWaves  = GRID * (BLOCK / 64);                 // 4096
    const int nGroups = (nBatch + nWaves * NB - 1) / (nWaves * NB);   // 2 at B=65536

    postpro_kernel<<<GRID, BLOCK, 0, stream>>>(prob, W1, b1, W2, b2, out, nBatch, nGroups);
}

// Round 16
// 25.588 us; speedup vs baseline: 16.7601x; 1.1166x over previous
//
#include <hip/hip_runtime.h>
#include <cstdint>
#include <cstddef>

typedef __attribute__((ext_vector_type(4))) float f32x4;
typedef __attribute__((ext_vector_type(3))) float f32x3;
typedef _Float16 h16x8 __attribute__((ext_vector_type(8)));
typedef _Float16 h16x2v __attribute__((ext_vector_type(2)));

#define BLOCK 256
#define GRID  2048
#define NB    8

__device__ __forceinline__ uint32_t pk16(float a, float b) {
    // lo half = cvt(a), hi half = cvt(b), round-toward-zero
    return __builtin_bit_cast(uint32_t, __builtin_amdgcn_cvt_pkrtz(a, b));
}

// packed f16 relu on an already-packed pair (cvt monotone, fixes 0 => commutes with relu)
__device__ __forceinline__ uint32_t pkmax0(uint32_t x) {
    h16x2v v = __builtin_bit_cast(h16x2v, x);
    const h16x2v z = {(_Float16)0.0f, (_Float16)0.0f};
    return __builtin_bit_cast(uint32_t, __builtin_elementwise_max(v, z));
}

union H8 { h16x8 v; uint32_t q[4]; };

// Lane l: p16 = l&15, g = l>>4.  One batch-group of NB=8 per wave (GRID 2048
// x 4 waves x 8 = 65536); grid-stride k-loop kept for generic B (runs once).
// H via MFMA (K=5), mu h-map chunk s slot j <-> h = 32s + 16*(j>>2) + 4g + (j&3).
// Softmax denominator via ones-row (A row c=3) in the epilogue MFMA:
// D[3][m] = sum_k e[k][m]; out = D[c] * rcp(D[3]); b2-fold survives exactly.
__global__ __launch_bounds__(BLOCK, 4) void postpro_kernel(
    const float* __restrict__ prob,
    const float* __restrict__ W1,
    const float* __restrict__ b1,
    const float* __restrict__ W2,
    const float* __restrict__ b2,
    float* __restrict__ out,
    int nBatch, int nGroups)
{
    __shared__ float sw[640];    // [0:512) W1 rows 0..3, [512:640) b1
    __shared__ float sW2[384];   // W2 [128][3] row-major
    const int tid = threadIdx.x;
    for (int i = tid; i < 512; i += BLOCK) sw[i] = W1[i];
    for (int i = tid; i < 128; i += BLOCK) sw[512 + i] = b1[i];
    for (int i = tid; i < 384; i += BLOCK) sW2[i] = W2[i];

    const int lane = tid & 63;
    const int p16  = lane & 15;
    const int g    = lane >> 4;
    const float fn = (float)p16;
    const bool g0  = (g == 0);

    const int wave   = blockIdx.x * (BLOCK / 64) + (tid >> 6);
    const int nWaves = GRID * (BLOCK / 64);   // 8192

    // group-0 prob loads issued pre-barrier (no LDS dependency)
    float pc0[NB], pc1[NB], pc2[NB];
    #pragma unroll
    for (int u = 0; u < NB; ++u) {
        int b = wave * NB + u; if (b > nBatch - 1) b = nBatch - 1;
        const float* pp = prob + (size_t)b * 48 + p16 * 3;
        pc0[u] = pp[0]; pc1[u] = pp[1]; pc2[u] = pp[2];
    }

    __syncthreads();   // LDS ready (the only barrier)

    // W1aug A-frags (once per wave): tile T, lane p16 -> row h = 16T + p16
    H8 wf[8];
    #pragma unroll
    for (int T = 0; T < 8; ++T) {
        const int h = 16 * T + p16;
        wf[T].q[0] = g0 ? pk16(sw[h],       sw[128 + h]) : 0u;
        wf[T].q[1] = g0 ? pk16(sw[256 + h], sw[384 + h]) : 0u;
        wf[T].q[2] = g0 ? pk16(sw[512 + h], 0.0f)        : 0u;
        wf[T].q[3] = 0u;
    }
    // W2 B-frags with the mu h-map
    const bool cc = (p16 < 3);
    H8 w2f[4];
    #pragma unroll
    for (int s = 0; s < 4; ++s) {
        const int hb = 32 * s + 4 * g;
        w2f[s].q[0] = cc ? pk16(sW2[(hb +  0) * 3 + p16], sW2[(hb +  1) * 3 + p16]) : 0u;
        w2f[s].q[1] = cc ? pk16(sW2[(hb +  2) * 3 + p16], sW2[(hb +  3) * 3 + p16]) : 0u;
        w2f[s].q[2] = cc ? pk16(sW2[(hb + 16) * 3 + p16], sW2[(hb + 17) * 3 + p16]) : 0u;
        w2f[s].q[3] = cc ? pk16(sW2[(hb + 18) * 3 + p16], sW2[(hb + 19) * 3 + p16]) : 0u;
    }
    const float binit = cc ? b2[p16] : 0.0f;       // b2 fold (exact through post-normalization)
    const f32x4 yinit = {binit, binit, binit, binit};
    const f32x4 zero4 = {0.f, 0.f, 0.f, 0.f};
    const uint32_t ones0 = (p16 == 3) ? 0x3C003C00u : 0u;   // epilogue ones-row (k=0..3)

    #pragma unroll 1
    for (int k = 0; k < nGroups; ++k) {
        const int G = wave + k * nWaves;

        if (k != 0) {   // generic-B path; not taken at B=65536
            #pragma unroll
            for (int u = 0; u < NB; ++u) {
                int b = G * NB + u; if (b > nBatch - 1) b = nBatch - 1;
                const float* pp = prob + (size_t)b * 48 + p16 * 3;
                pc0[u] = pp[0]; pc1[u] = pp[1]; pc2[u] = pp[2];
            }
        }

        // pack this group's xaug B-frags
        H8 xf[NB];
        #pragma unroll
        for (int u = 0; u < NB; ++u) {
            xf[u].q[0] = g0 ? pk16(pc0[u], pc1[u]) : 0u;
            xf[u].q[1] = g0 ? pk16(pc2[u], fn) : 0u;
            xf[u].q[2] = g0 ? 0x00003C00u : 0u;   // (1.0h, 0)
            xf[u].q[3] = 0u;
        }

        #pragma unroll
        for (int u = 0; u < NB; ++u) {
            // H tiles on the matrix pipe (8 independent MFMAs, K=5 useful)
            f32x4 hD[8];
            #pragma unroll
            for (int T = 0; T < 8; ++T)
                hD[T] = __builtin_amdgcn_mfma_f32_16x16x32_f16(wf[T].v, xf[u].v, zero4, 0, 0, 0);

            f32x4 accS = zero4, accY = yinit;
            #pragma unroll
            for (int s = 0; s < 4; ++s) {
                const f32x4 d0 = hD[2 * s], d1 = hD[2 * s + 1];
                H8 Hf;   // pack then packed-relu (v_pk_max_f16)
                Hf.q[0] = pkmax0(pk16(d0[0], d0[1]));
                Hf.q[1] = pkmax0(pk16(d0[2], d0[3]));
                Hf.q[2] = pkmax0(pk16(d1[0], d1[1]));
                Hf.q[3] = pkmax0(pk16(d1[2], d1[3]));

                accS = __builtin_amdgcn_mfma_f32_16x16x32_f16(Hf.v, Hf.v,     accS, 0, 0, 0);
                accY = __builtin_amdgcn_mfma_f32_16x16x32_f16(Hf.v, w2f[s].v, accY, 0, 0, 0);
            }

            // transposed softmax, numerator only: accS[r] = S[p16][4g+r] (symmetric)
            float m0 = fmaxf(fmaxf(accS[0], accS[1]), fmaxf(accS[2], accS[3]));
            m0 = fmaxf(m0, __shfl_xor(m0, 16));
            m0 = fmaxf(m0, __shfl_xor(m0, 32));
            const float e0 = __expf(accS[0] - m0);   // <= 1: f16-safe
            const float e1 = __expf(accS[1] - m0);
            const float e2 = __expf(accS[2] - m0);
            const float e3 = __expf(accS[3] - m0);

            // epilogue: D[c][m] = sum_k A[c][k] e[k][m]; A rows 0..2 = Y'^T, row 3 = ones
            H8 Afr, Bfr;
            Afr.q[0] = cc ? pk16(accY[0], accY[1]) : ones0;
            Afr.q[1] = cc ? pk16(accY[2], accY[3]) : ones0;
            Afr.q[2] = 0u; Afr.q[3] = 0u;
            Bfr.q[0] = pk16(e0, e1);
            Bfr.q[1] = pk16(e2, e3);
            Bfr.q[2] = 0u; Bfr.q[3] = 0u;

            const f32x4 D = __builtin_amdgcn_mfma_f32_16x16x32_f16(Afr.v, Bfr.v, zero4, 0, 0, 0);
            // D reg r, lane p16 (g==0): r=0..2 -> unnormalized out[m=p16][c=r], r=3 -> sum(e)

            const int b = G * NB + u;
            if (g0 && b < nBatch) {
                const float inv = __builtin_amdgcn_rcpf(D[3]);
                float* dst = out + (size_t)b * 48 + p16 * 3;
                f32x3 v = {D[0] * inv, D[1] * inv, D[2] * inv};
                *(f32x3*)dst = v;
            }
        }
    }
}

extern "C" void kernel_launch(void* const* d_in, const int* in_sizes, int n_in,
                              void* d_out, int out_size, void* d_ws, size_t ws_size,
                              hipStream_t stream) {
    const float* prob = (const float*)d_in[0];
    const float* W1   = (const float*)d_in[1];
    const float* b1   = (const float*)d_in[2];
    const float* W2   = (const float*)d_in[3];
    const float* b2   = (const float*)d_in[4];
    float* out        = (float*)d_out;

    const int nBatch  = in_sizes[0] / 48;                    // [B,16,3] -> 65536
    const int nWaves  = GRID * (BLOCK / 64);                 // 8192
    const int nGroups = (nBatch + nWaves * NB - 1) / (nWaves * NB);   // 1 at B=65536

    postpro_kernel<<<GRID, BLOCK, 0, stream>>>(prob, W1, b1, W2, b2, out, nBatch, nGroups);
}

// Round 17
// 25.304 us; speedup vs baseline: 16.9482x; 1.0112x over previous
//
#include <hip/hip_runtime.h>
#include <cstdint>
#include <cstddef>

typedef __attribute__((ext_vector_type(4))) float f32x4;
typedef __attribute__((ext_vector_type(3))) float f32x3;
typedef _Float16 h16x8 __attribute__((ext_vector_type(8)));
typedef _Float16 h16x2v __attribute__((ext_vector_type(2)));

#define BLOCK 256
#define GRID  2048
#define NB    8

__device__ __forceinline__ uint32_t pk16(float a, float b) {
    // lo half = cvt(a), hi half = cvt(b), round-toward-zero
    return __builtin_bit_cast(uint32_t, __builtin_amdgcn_cvt_pkrtz(a, b));
}

// packed f16 relu on an already-packed pair (cvt monotone, fixes 0 => commutes with relu)
__device__ __forceinline__ uint32_t pkmax0(uint32_t x) {
    h16x2v v = __builtin_bit_cast(h16x2v, x);
    const h16x2v z = {(_Float16)0.0f, (_Float16)0.0f};
    return __builtin_bit_cast(uint32_t, __builtin_elementwise_max(v, z));
}

union H8 { h16x8 v; uint32_t q[4]; };

// Lane l: p16 = l&15, g = l>>4.  One batch-group of NB=8 per wave
// (GRID 2048 x 4 waves x NB 8 = 65536 = B exactly; clamps guard smaller B).
// H via MFMA (K=5), mu h-map chunk s slot j <-> h = 32s + 16*(j>>2) + 4g + (j&3).
// H-MFMAs interleaved with their consuming chunk (hD liveness 8 regs, not 32);
// xf built inline per u (no live xf[NB] array) — register diet for residency.
// Softmax denominator via ones-row (A row c=3) in the epilogue MFMA:
// D[3][m] = sum_k e[k][m]; out = D[c] * rcp(D[3]); b2-fold survives exactly.
__global__ __launch_bounds__(BLOCK, 4) void postpro_kernel(
    const float* __restrict__ prob,
    const float* __restrict__ W1,
    const float* __restrict__ b1,
    const float* __restrict__ W2,
    const float* __restrict__ b2,
    float* __restrict__ out,
    int nBatch)
{
    __shared__ float sw[640];    // [0:512) W1 rows 0..3, [512:640) b1
    __shared__ float sW2[384];   // W2 [128][3] row-major
    const int tid = threadIdx.x;
    for (int i = tid; i < 512; i += BLOCK) sw[i] = W1[i];
    for (int i = tid; i < 128; i += BLOCK) sw[512 + i] = b1[i];
    for (int i = tid; i < 384; i += BLOCK) sW2[i] = W2[i];

    const int lane = tid & 63;
    const int p16  = lane & 15;
    const int g    = lane >> 4;
    const float fn = (float)p16;
    const bool g0  = (g == 0);

    const int wave = blockIdx.x * (BLOCK / 64) + (tid >> 6);

    // prob loads issued pre-barrier (no LDS dependency)
    float pc0[NB], pc1[NB], pc2[NB];
    #pragma unroll
    for (int u = 0; u < NB; ++u) {
        int b = wave * NB + u; if (b > nBatch - 1) b = nBatch - 1;
        const float* pp = prob + (size_t)b * 48 + p16 * 3;
        pc0[u] = pp[0]; pc1[u] = pp[1]; pc2[u] = pp[2];
    }

    __syncthreads();   // LDS ready (the only barrier)

    // W1aug A-frags (once per wave): tile T, lane p16 -> row h = 16T + p16
    H8 wf[8];
    #pragma unroll
    for (int T = 0; T < 8; ++T) {
        const int h = 16 * T + p16;
        wf[T].q[0] = g0 ? pk16(sw[h],       sw[128 + h]) : 0u;
        wf[T].q[1] = g0 ? pk16(sw[256 + h], sw[384 + h]) : 0u;
        wf[T].q[2] = g0 ? pk16(sw[512 + h], 0.0f)        : 0u;
        wf[T].q[3] = 0u;
    }
    // W2 B-frags with the mu h-map
    const bool cc = (p16 < 3);
    H8 w2f[4];
    #pragma unroll
    for (int s = 0; s < 4; ++s) {
        const int hb = 32 * s + 4 * g;
        w2f[s].q[0] = cc ? pk16(sW2[(hb +  0) * 3 + p16], sW2[(hb +  1) * 3 + p16]) : 0u;
        w2f[s].q[1] = cc ? pk16(sW2[(hb +  2) * 3 + p16], sW2[(hb +  3) * 3 + p16]) : 0u;
        w2f[s].q[2] = cc ? pk16(sW2[(hb + 16) * 3 + p16], sW2[(hb + 17) * 3 + p16]) : 0u;
        w2f[s].q[3] = cc ? pk16(sW2[(hb + 18) * 3 + p16], sW2[(hb + 19) * 3 + p16]) : 0u;
    }
    const float binit = cc ? b2[p16] : 0.0f;       // b2 fold (exact through post-normalization)
    const f32x4 yinit = {binit, binit, binit, binit};
    const f32x4 zero4 = {0.f, 0.f, 0.f, 0.f};
    const uint32_t ones0 = (p16 == 3) ? 0x3C003C00u : 0u;   // epilogue ones-row (k=0..3)

    #pragma unroll
    for (int u = 0; u < NB; ++u) {
        // xaug B-frag built inline (4 ops; no live array across the loop)
        H8 xfu;
        xfu.q[0] = g0 ? pk16(pc0[u], pc1[u]) : 0u;
        xfu.q[1] = g0 ? pk16(pc2[u], fn) : 0u;
        xfu.q[2] = g0 ? 0x00003C00u : 0u;   // (1.0h, 0)
        xfu.q[3] = 0u;

        f32x4 accS = zero4, accY = yinit;
        #pragma unroll
        for (int s = 0; s < 4; ++s) {
            // H tiles 2s, 2s+1 issued right before their consumption (liveness diet)
            const f32x4 d0 = __builtin_amdgcn_mfma_f32_16x16x32_f16(wf[2 * s].v,     xfu.v, zero4, 0, 0, 0);
            const f32x4 d1 = __builtin_amdgcn_mfma_f32_16x16x32_f16(wf[2 * s + 1].v, xfu.v, zero4, 0, 0, 0);

            H8 Hf;   // pack then packed-relu (v_pk_max_f16)
            Hf.q[0] = pkmax0(pk16(d0[0], d0[1]));
            Hf.q[1] = pkmax0(pk16(d0[2], d0[3]));
            Hf.q[2] = pkmax0(pk16(d1[0], d1[1]));
            Hf.q[3] = pkmax0(pk16(d1[2], d1[3]));

            accS = __builtin_amdgcn_mfma_f32_16x16x32_f16(Hf.v, Hf.v,     accS, 0, 0, 0);
            accY = __builtin_amdgcn_mfma_f32_16x16x32_f16(Hf.v, w2f[s].v, accY, 0, 0, 0);
        }

        // transposed softmax, numerator only: accS[r] = S[p16][4g+r] (symmetric)
        float m0 = fmaxf(fmaxf(accS[0], accS[1]), fmaxf(accS[2], accS[3]));
        m0 = fmaxf(m0, __shfl_xor(m0, 16));
        m0 = fmaxf(m0, __shfl_xor(m0, 32));
        const float e0 = __expf(accS[0] - m0);   // <= 1: f16-safe
        const float e1 = __expf(accS[1] - m0);
        const float e2 = __expf(accS[2] - m0);
        const float e3 = __expf(accS[3] - m0);

        // epilogue: D[c][m] = sum_k A[c][k] e[k][m]; A rows 0..2 = Y'^T, row 3 = ones
        H8 Afr, Bfr;
        Afr.q[0] = cc ? pk16(accY[0], accY[1]) : ones0;
        Afr.q[1] = cc ? pk16(accY[2], accY[3]) : ones0;
        Afr.q[2] = 0u; Afr.q[3] = 0u;
        Bfr.q[0] = pk16(e0, e1);
        Bfr.q[1] = pk16(e2, e3);
        Bfr.q[2] = 0u; Bfr.q[3] = 0u;

        const f32x4 D = __builtin_amdgcn_mfma_f32_16x16x32_f16(Afr.v, Bfr.v, zero4, 0, 0, 0);
        // D reg r, lane p16 (g==0): r=0..2 -> unnormalized out[m=p16][c=r], r=3 -> sum(e)

        const int b = wave * NB + u;
        if (g0 && b < nBatch) {
            const float inv = __builtin_amdgcn_rcpf(D[3]);
            float* dst = out + (size_t)b * 48 + p16 * 3;
            f32x3 v = {D[0] * inv, D[1] * inv, D[2] * inv};
            *(f32x3*)dst = v;
        }
    }
}

extern "C" void kernel_launch(void* const* d_in, const int* in_sizes, int n_in,
                              void* d_out, int out_size, void* d_ws, size_t ws_size,
                              hipStream_t stream) {
    const float* prob = (const float*)d_in[0];
    const float* W1   = (const float*)d_in[1];
    const float* b1   = (const float*)d_in[2];
    const float* W2   = (const float*)d_in[3];
    const float* b2   = (const float*)d_in[4];
    float* out        = (float*)d_out;

    const int nBatch = in_sizes[0] / 48;   // [B,16,3] -> 65536 = GRID*4*NB exactly
    postpro_kernel<<<GRID, BLOCK, 0, stream>>>(prob, W1, b1, W2, b2, out, nBatch);
}

// Round 18
// 23.416 us; speedup vs baseline: 18.3153x; 1.0807x over previous
//
#include <hip/hip_runtime.h>
#include <cstdint>
#include <cstddef>

typedef __attribute__((ext_vector_type(4))) float f32x4;
typedef __attribute__((ext_vector_type(3))) float f32x3;
typedef _Float16 h16x8 __attribute__((ext_vector_type(8)));
typedef _Float16 h16x2v __attribute__((ext_vector_type(2)));

#define BLOCK 256
#define GRID  2048
#define NB    8

__device__ __forceinline__ uint32_t pk16(float a, float b) {
    // lo half = cvt(a), hi half = cvt(b), round-toward-zero
    return __builtin_bit_cast(uint32_t, __builtin_amdgcn_cvt_pkrtz(a, b));
}

// packed f16 relu on an already-packed pair (cvt monotone, fixes 0 => commutes with relu)
__device__ __forceinline__ uint32_t pkmax0(uint32_t x) {
    h16x2v v = __builtin_bit_cast(h16x2v, x);
    const h16x2v z = {(_Float16)0.0f, (_Float16)0.0f};
    return __builtin_bit_cast(uint32_t, __builtin_elementwise_max(v, z));
}

union H8 { h16x8 v; uint32_t q[4]; };

// Lane l: p16 = l&15, g = l>>4.  One batch-group of NB=8 per wave
// (GRID 2048 x 4 waves x NB 8 = 65536 = B exactly; clamps guard smaller B).
// NO LDS, NO barriers: weight fragments built from direct global loads
// (2.5 KB total, shared by all blocks -> L2/L3-resident after first touch);
// waves proceed fully independently.
// H via MFMA (K=5), mu h-map chunk s slot j <-> h = 32s + 16*(j>>2) + 4g + (j&3).
// Softmax denominator via ones-row (A row c=3) in the epilogue MFMA:
// D[3][m] = sum_k e[k][m]; out = D[c] * rcp(D[3]); b2-fold survives exactly.
__global__ __launch_bounds__(BLOCK, 4) void postpro_kernel(
    const float* __restrict__ prob,
    const float* __restrict__ W1,
    const float* __restrict__ b1,
    const float* __restrict__ W2,
    const float* __restrict__ b2,
    float* __restrict__ out,
    int nBatch)
{
    const int tid  = threadIdx.x;
    const int lane = tid & 63;
    const int p16  = lane & 15;
    const int g    = lane >> 4;
    const float fn = (float)p16;
    const bool g0  = (g == 0);
    const bool cc  = (p16 < 3);

    const int wave = blockIdx.x * (BLOCK / 64) + (tid >> 6);

    // per-wave prob loads (issued first: HBM-bound first touch)
    float pc0[NB], pc1[NB], pc2[NB];
    #pragma unroll
    for (int u = 0; u < NB; ++u) {
        int b = wave * NB + u; if (b > nBatch - 1) b = nBatch - 1;
        const float* pp = prob + (size_t)b * 48 + p16 * 3;
        pc0[u] = pp[0]; pc1[u] = pp[1]; pc2[u] = pp[2];
    }

    // W1aug A-frags from global (g0 lanes): tile T, lane p16 -> row h = 16T + p16
    H8 wf[8];
    if (g0) {
        #pragma unroll
        for (int T = 0; T < 8; ++T) {
            const int h = 16 * T + p16;
            wf[T].q[0] = pk16(W1[h],       W1[128 + h]);
            wf[T].q[1] = pk16(W1[256 + h], W1[384 + h]);
            wf[T].q[2] = pk16(b1[h], 0.0f);
            wf[T].q[3] = 0u;
        }
    } else {
        #pragma unroll
        for (int T = 0; T < 8; ++T) {
            wf[T].q[0] = 0u; wf[T].q[1] = 0u; wf[T].q[2] = 0u; wf[T].q[3] = 0u;
        }
    }

    // W2 B-frags from global (cc lanes), mu h-map: chunk s slot j -> h = 32s+16*(j>>2)+4g+(j&3)
    H8 w2f[4];
    if (cc) {
        #pragma unroll
        for (int s = 0; s < 4; ++s) {
            const int hb = 32 * s + 4 * g;
            w2f[s].q[0] = pk16(W2[(hb +  0) * 3 + p16], W2[(hb +  1) * 3 + p16]);
            w2f[s].q[1] = pk16(W2[(hb +  2) * 3 + p16], W2[(hb +  3) * 3 + p16]);
            w2f[s].q[2] = pk16(W2[(hb + 16) * 3 + p16], W2[(hb + 17) * 3 + p16]);
            w2f[s].q[3] = pk16(W2[(hb + 18) * 3 + p16], W2[(hb + 19) * 3 + p16]);
        }
    } else {
        #pragma unroll
        for (int s = 0; s < 4; ++s) {
            w2f[s].q[0] = 0u; w2f[s].q[1] = 0u; w2f[s].q[2] = 0u; w2f[s].q[3] = 0u;
        }
    }

    const float binit = cc ? b2[p16] : 0.0f;       // b2 fold (exact through post-normalization)
    const f32x4 yinit = {binit, binit, binit, binit};
    const f32x4 zero4 = {0.f, 0.f, 0.f, 0.f};
    const uint32_t ones0 = (p16 == 3) ? 0x3C003C00u : 0u;   // epilogue ones-row (k=0..3)

    #pragma unroll
    for (int u = 0; u < NB; ++u) {
        // xaug B-frag built inline
        H8 xfu;
        xfu.q[0] = g0 ? pk16(pc0[u], pc1[u]) : 0u;
        xfu.q[1] = g0 ? pk16(pc2[u], fn) : 0u;
        xfu.q[2] = g0 ? 0x00003C00u : 0u;   // (1.0h, 0)
        xfu.q[3] = 0u;

        f32x4 accS = zero4, accY = yinit;
        #pragma unroll
        for (int s = 0; s < 4; ++s) {
            // H tiles 2s, 2s+1 issued right before their consumption
            const f32x4 d0 = __builtin_amdgcn_mfma_f32_16x16x32_f16(wf[2 * s].v,     xfu.v, zero4, 0, 0, 0);
            const f32x4 d1 = __builtin_amdgcn_mfma_f32_16x16x32_f16(wf[2 * s + 1].v, xfu.v, zero4, 0, 0, 0);

            H8 Hf;   // pack then packed-relu (v_pk_max_f16)
            Hf.q[0] = pkmax0(pk16(d0[0], d0[1]));
            Hf.q[1] = pkmax0(pk16(d0[2], d0[3]));
            Hf.q[2] = pkmax0(pk16(d1[0], d1[1]));
            Hf.q[3] = pkmax0(pk16(d1[2], d1[3]));

            accS = __builtin_amdgcn_mfma_f32_16x16x32_f16(Hf.v, Hf.v,     accS, 0, 0, 0);
            accY = __builtin_amdgcn_mfma_f32_16x16x32_f16(Hf.v, w2f[s].v, accY, 0, 0, 0);
        }

        // transposed softmax, numerator only: accS[r] = S[p16][4g+r] (symmetric)
        float m0 = fmaxf(fmaxf(accS[0], accS[1]), fmaxf(accS[2], accS[3]));
        m0 = fmaxf(m0, __shfl_xor(m0, 16));
        m0 = fmaxf(m0, __shfl_xor(m0, 32));
        const float e0 = __expf(accS[0] - m0);   // <= 1: f16-safe
        const float e1 = __expf(accS[1] - m0);
        const float e2 = __expf(accS[2] - m0);
        const float e3 = __expf(accS[3] - m0);

        // epilogue: D[c][m] = sum_k A[c][k] e[k][m]; A rows 0..2 = Y'^T, row 3 = ones
        H8 Afr, Bfr;
        Afr.q[0] = cc ? pk16(accY[0], accY[1]) : ones0;
        Afr.q[1] = cc ? pk16(accY[2], accY[3]) : ones0;
        Afr.q[2] = 0u; Afr.q[3] = 0u;
        Bfr.q[0] = pk16(e0, e1);
        Bfr.q[1] = pk16(e2, e3);
        Bfr.q[2] = 0u; Bfr.q[3] = 0u;

        const f32x4 D = __builtin_amdgcn_mfma_f32_16x16x32_f16(Afr.v, Bfr.v, zero4, 0, 0, 0);
        // D reg r, lane p16 (g==0): r=0..2 -> unnormalized out[m=p16][c=r], r=3 -> sum(e)

        const int b = wave * NB + u;
        if (g0 && b < nBatch) {
            const float inv = __builtin_amdgcn_rcpf(D[3]);
            float* dst = out + (size_t)b * 48 + p16 * 3;
            f32x3 v = {D[0] * inv, D[1] * inv, D[2] * inv};
            *(f32x3*)dst = v;
        }
    }
}

extern "C" void kernel_launch(void* const* d_in, const int* in_sizes, int n_in,
                              void* d_out, int out_size, void* d_ws, size_t ws_size,
                              hipStream_t stream) {
    const float* prob = (const float*)d_in[0];
    const float* W1   = (const float*)d_in[1];
    const float* b1   = (const float*)d_in[2];
    const float* W2   = (const float*)d_in[3];
    const float* b2   = (const float*)d_in[4];
    float* out        = (float*)d_out;

    const int nBatch = in_sizes[0] / 48;   // [B,16,3] -> 65536 = GRID*4*NB exactly
    postpro_kernel<<<GRID, BLOCK, 0, stream>>>(prob, W1, b1, W2, b2, out, nBatch);
}